// Round 5
// baseline (664.838 us; speedup 1.0000x reference)
//
#include <hip/hip_runtime.h>

#define D 64
#define TPB 256
#define EPB 2048            // edges per build block
#define EPT 8               // edges per thread in build blocks
#define BINSZ 128           // nodes per bin (power of 2: bin = dst >> 7)
#define NBIN_MAX 640        // LDS sizing (actual 625)

// ---------------- K1: per-(block,bin) histogram ----------------
__global__ __launch_bounds__(TPB) void binhist_kernel(
    const int* __restrict__ dst, int* __restrict__ blockbin,
    int n_edges, int nbin, int eb)
{
    __shared__ int hist[NBIN_MAX];
    int t = threadIdx.x, blk = blockIdx.x;
    for (int i = t; i < nbin; i += TPB) hist[i] = 0;
    __syncthreads();
    int base = blk * EPB;
    #pragma unroll
    for (int k = 0; k < EPT; ++k) {
        int e = base + k * TPB + t;
        if (e < n_edges) atomicAdd(&hist[dst[e] >> 7], 1);
    }
    __syncthreads();
    for (int i = t; i < nbin; i += TPB) blockbin[i * eb + blk] = hist[i];
}

// ---------------- generic 3-kernel exclusive scan ----------------
__global__ __launch_bounds__(TPB) void scan_up(
    const int* __restrict__ in, int* __restrict__ out,
    int* __restrict__ partials, int n)
{
    __shared__ int tsum[TPB];
    int t = threadIdx.x;
    int base = blockIdx.x * (TPB * 4) + t * 4;
    int v[4];
    #pragma unroll
    for (int i = 0; i < 4; ++i) v[i] = (base + i < n) ? in[base + i] : 0;
    int tot = v[0] + v[1] + v[2] + v[3];
    tsum[t] = tot;
    __syncthreads();
    for (int off = 1; off < TPB; off <<= 1) {
        int x = (t >= off) ? tsum[t - off] : 0;
        __syncthreads();
        tsum[t] += x;
        __syncthreads();
    }
    if (t == TPB - 1) partials[blockIdx.x] = tsum[t];
    int run = tsum[t] - tot;
    #pragma unroll
    for (int i = 0; i < 4; ++i) {
        if (base + i < n) out[base + i] = run;
        run += v[i];
    }
}

__global__ __launch_bounds__(1024) void scan_mid(int* __restrict__ partials, int nb)
{
    __shared__ int tsum[1024];
    int t = threadIdx.x;
    int v = (t < nb) ? partials[t] : 0;
    tsum[t] = v;
    __syncthreads();
    for (int off = 1; off < 1024; off <<= 1) {
        int x = (t >= off) ? tsum[t - off] : 0;
        __syncthreads();
        tsum[t] += x;
        __syncthreads();
    }
    if (t < nb) partials[t] = tsum[t] - v;   // exclusive
}

__global__ __launch_bounds__(TPB) void scan_down(
    int* __restrict__ out, const int* __restrict__ partials, int n)
{
    int t = threadIdx.x;
    int base = blockIdx.x * (TPB * 4) + t * 4;
    int add = partials[blockIdx.x];
    #pragma unroll
    for (int i = 0; i < 4; ++i)
        if (base + i < n) out[base + i] += add;
}

// ---------------- K5: bin-scatter with LDS reorder ----------------
// Deterministic bases: each (block,bin) pair has an exact precomputed base
// from the global scan; records staged in LDS grouped by bin, then written as
// contiguous runs. XCD-chunked swizzle keeps adjacent runs' writers on the
// same XCD L2 so partial 64B lines merge before writeback.
__global__ __launch_bounds__(TPB) void binscatter_kernel(
    const int* __restrict__ src, const int* __restrict__ dst,
    const float* __restrict__ edge_w, const int* __restrict__ scanned,
    uint2* __restrict__ csr, int n_edges, int nbin, int eb)
{
    __shared__ int lb[NBIN_MAX + 1];
    __shared__ int cur[NBIN_MAX];
    __shared__ unsigned short binof[EPB];
    __shared__ uint2 stage[EPB];
    __shared__ int tv[TPB];

    int t = threadIdx.x;
    // bijective chunked XCD swizzle (m204 formula)
    int q = eb >> 3, r = eb & 7;
    int xcd = blockIdx.x & 7, sub = blockIdx.x >> 3;
    int blk = (xcd < r ? xcd * (q + 1) : r * (q + 1) + (xcd - r) * q) + sub;

    for (int i = t; i < nbin + 1; i += TPB) lb[i] = 0;
    __syncthreads();

    int base = blk * EPB;
    int d[EPT], s[EPT]; float w[EPT];
    #pragma unroll
    for (int k = 0; k < EPT; ++k) {
        int e = base + k * TPB + t;
        bool ok = (e < n_edges);
        d[k] = ok ? dst[e] : -1;
        s[k] = ok ? src[e] : 0;
        w[k] = ok ? edge_w[e] : 0.0f;
        if (ok) atomicAdd(&lb[d[k] >> 7], 1);
    }
    __syncthreads();

    // local exclusive scan of lb[0..nbin) ; total -> lb[nbin]
    int b3 = t * 3;
    int v0 = (b3     < nbin) ? lb[b3]     : 0;
    int v1 = (b3 + 1 < nbin) ? lb[b3 + 1] : 0;
    int v2 = (b3 + 2 < nbin) ? lb[b3 + 2] : 0;
    int tot = v0 + v1 + v2;
    tv[t] = tot;
    __syncthreads();
    for (int off = 1; off < TPB; off <<= 1) {
        int x = (t >= off) ? tv[t - off] : 0;
        __syncthreads();
        tv[t] += x;
        __syncthreads();
    }
    int exc = tv[t] - tot;
    if (b3     < nbin) lb[b3]     = exc;
    if (b3 + 1 < nbin) lb[b3 + 1] = exc + v0;
    if (b3 + 2 < nbin) lb[b3 + 2] = exc + v0 + v1;
    if (t == TPB - 1)  lb[nbin]   = tv[t];
    __syncthreads();

    for (int i = t; i < nbin; i += TPB) cur[i] = lb[i];
    __syncthreads();

    #pragma unroll
    for (int k = 0; k < EPT; ++k) {
        if (d[k] >= 0) {
            int bin = d[k] >> 7;
            int pos = atomicAdd(&cur[bin], 1);
            stage[pos] = make_uint2((unsigned)s[k] | ((unsigned)(d[k] & (BINSZ - 1)) << 17),
                                    __float_as_uint(w[k]));
            binof[pos] = (unsigned short)bin;
        }
    }
    __syncthreads();

    int nval = lb[nbin];
    for (int p = t; p < nval; p += TPB) {
        int bin = binof[p];
        int gpos = scanned[bin * eb + blk] + (p - lb[bin]);
        csr[gpos] = stage[p];
    }
}

// ---------------- K6: per-bin LDS-accumulate + GEMM + sigmoid ----------------
__global__ __launch_bounds__(TPB) void bin_aggregate_kernel(
    const float* __restrict__ feats, const int* __restrict__ scanned,
    const uint2* __restrict__ csr, const float* __restrict__ Wm,
    const float* __restrict__ bv, float* __restrict__ out,
    int n_nodes, int n_edges, int nbin, int eb)
{
    __shared__ float acc[BINSZ][D];   // 32 KiB; bank: (dl*64+lane)%32 = lane%32 -> 2 lanes/bank (free)
    __shared__ float swd[BINSZ];

    int t = threadIdx.x, lane = t & 63, wv = t >> 6;
    int bin = blockIdx.x;
    int lo  = bin << 7;

    float wcol[D];
    #pragma unroll
    for (int k2 = 0; k2 < D; ++k2) wcol[k2] = Wm[k2 * D + lane];
    float bias = bv[lane];

    for (int i = t; i < BINSZ * D; i += TPB) ((float*)acc)[i] = 0.0f;
    for (int i = t; i < BINSZ; i += TPB) swd[i] = 0.0f;
    __syncthreads();

    int seg0 = scanned[bin * eb];
    int seg1 = (bin + 1 < nbin) ? scanned[(bin + 1) * eb] : n_edges;

    // each wave: 64-edge chunks, strided; lane ln owns record ln of the chunk
    for (int cb = seg0 + wv * 64; cb < seg1; cb += 256) {
        int idx = cb + lane;
        uint2 rec = (idx < seg1) ? csr[idx] : make_uint2(0u, 0u);  // w=0 -> no-op

        // per-lane sum_w contribution (one LDS atomic per edge, all lanes parallel)
        atomicAdd(&swd[rec.x >> 17], __uint_as_float(rec.y));

        for (int j2 = 0; j2 < 4; ++j2) {
            #pragma unroll
            for (int j = 0; j < 16; ++j) {
                int ln = j2 * 16 + j;   // uniform
                unsigned ex = __builtin_amdgcn_readlane(rec.x, ln);
                float    wj = __uint_as_float(__builtin_amdgcn_readlane(rec.y, ln));
                int dl   = (int)(ex >> 17);
                int sidx = (int)(ex & 0x1FFFF);
                float v  = wj * feats[sidx * D + lane];   // coalesced 256B row gather
                atomicAdd(&acc[dl][lane], v);             // ds_add_f32, conflict-free
            }
        }
    }
    __syncthreads();

    // epilogue: wave wv owns local nodes [wv*32, wv*32+32)
    for (int rsub = 0; rsub < 32; ++rsub) {
        int nl = wv * 32 + rsub;
        int n  = lo + nl;
        if (n >= n_nodes) break;
        float a  = acc[nl][lane];
        float sw = swd[nl];
        float f  = feats[n * D + lane];
        float h  = (sw > 0.0f) ? a / fmaxf(sw, 1e-30f) : 0.0f;
        float aggv = 0.8f * f + 0.2f * h;
        float racc = bias;
        #pragma unroll
        for (int k2 = 0; k2 < D; ++k2) {
            float ak = __uint_as_float(
                __builtin_amdgcn_readlane(__float_as_uint(aggv), k2));
            racc = fmaf(ak, wcol[k2], racc);
        }
        out[n * D + lane] = 1.0f / (1.0f + __expf(-racc));
    }
}

extern "C" void kernel_launch(void* const* d_in, const int* in_sizes, int n_in,
                              void* d_out, int out_size, void* d_ws, size_t ws_size,
                              hipStream_t stream)
{
    const float* feats  = (const float*)d_in[0];
    const int*   src    = (const int*)d_in[1];
    const int*   dst    = (const int*)d_in[2];
    const float* edge_w = (const float*)d_in[3];
    const float* W      = (const float*)d_in[4];
    const float* b      = (const float*)d_in[5];
    float*       out    = (float*)d_out;

    const int n_nodes = in_sizes[0] / D;
    const int n_edges = in_sizes[1];

    const int NBIN = (n_nodes + BINSZ - 1) / BINSZ;       // 625
    const int EB   = (n_edges + EPB - 1) / EPB;           // 625
    const int NBB  = NBIN * EB;                           // 390,625
    const int nb   = (NBB + TPB * 4 - 1) / (TPB * 4);     // 382 (<=1024)

    // ---- workspace layout (ints; no memset needed: everything read is written) ----
    int* ws_i     = (int*)d_ws;
    int* blockbin = ws_i;                 // [NBB]
    int* scanned  = blockbin + NBB;       // [NBB]
    int* partials = scanned + NBB;        // [1024]
    uint2* csr    = (uint2*)(partials + 1024);   // [n_edges], 8B-aligned (2*NBB+1024 even)

    binhist_kernel<<<EB, TPB, 0, stream>>>(dst, blockbin, n_edges, NBIN, EB);
    scan_up<<<nb, TPB, 0, stream>>>(blockbin, scanned, partials, NBB);
    scan_mid<<<1, 1024, 0, stream>>>(partials, nb);
    scan_down<<<nb, TPB, 0, stream>>>(scanned, partials, NBB);
    binscatter_kernel<<<EB, TPB, 0, stream>>>(src, dst, edge_w, scanned, csr,
                                              n_edges, NBIN, EB);
    bin_aggregate_kernel<<<NBIN, TPB, 0, stream>>>(feats, scanned, csr, W, b,
                                                   out, n_nodes, n_edges, NBIN, EB);
}

// Round 7
// 586.831 us; speedup vs baseline: 1.1329x; 1.1329x over previous
//
#include <hip/hip_runtime.h>

#define D 64
#define TPB 256
#define EPB 1024            // edges per build chunk
#define EPT (EPB / TPB)     // 4 edges per thread in build blocks
#define BINSZ 64            // nodes per bin (bin = dst >> 6)
#define BINSHIFT 6
#define NBIN_MAX 1280       // LDS sizing (actual 1250)
#define SCAN_ITEMS 8

// bijective chunked XCD swizzle (m204): physical block -> logical chunk so
// that blocks resident on one XCD (round-robin dispatch) own CONTIGUOUS
// logical chunks. binhist and binscatter MUST use the same mapping.
__device__ __forceinline__ int xcd_chunk(int phys, int nblk)
{
    int q = nblk >> 3, r = nblk & 7;
    int xcd = phys & 7, sub = phys >> 3;
    return (xcd < r ? xcd * (q + 1) : r * (q + 1) + (xcd - r) * q) + sub;
}

// ---------------- K1: per-(chunk,bin) histogram ----------------
__global__ __launch_bounds__(TPB) void binhist_kernel(
    const int* __restrict__ dst, int* __restrict__ blockbin,
    int n_edges, int nbin, int eb)
{
    __shared__ int hist[NBIN_MAX];
    int t = threadIdx.x;
    int blk = xcd_chunk(blockIdx.x, eb);
    for (int i = t; i < nbin; i += TPB) hist[i] = 0;
    __syncthreads();
    int base = blk * EPB;
    #pragma unroll
    for (int k = 0; k < EPT; ++k) {
        int e = base + k * TPB + t;
        if (e < n_edges) atomicAdd(&hist[dst[e] >> BINSHIFT], 1);
    }
    __syncthreads();
    // scattered 4B writes, but 16 consecutive blk share a 64B line and sit on
    // one XCD thanks to the swizzle -> merge in its L2.
    for (int i = t; i < nbin; i += TPB) blockbin[i * eb + blk] = hist[i];
}

// ---------------- 3-kernel exclusive scan (in-place) ----------------
__global__ __launch_bounds__(TPB) void scan_up(
    int* __restrict__ data, int* __restrict__ partials, int n)
{
    __shared__ int tsum[TPB];
    int t = threadIdx.x;
    int base = blockIdx.x * (TPB * SCAN_ITEMS) + t * SCAN_ITEMS;
    int v[SCAN_ITEMS];
    #pragma unroll
    for (int i = 0; i < SCAN_ITEMS; ++i)
        v[i] = (base + i < n) ? data[base + i] : 0;
    int tot = 0;
    #pragma unroll
    for (int i = 0; i < SCAN_ITEMS; ++i) tot += v[i];
    tsum[t] = tot;
    __syncthreads();
    for (int off = 1; off < TPB; off <<= 1) {
        int x = (t >= off) ? tsum[t - off] : 0;
        __syncthreads();
        tsum[t] += x;
        __syncthreads();
    }
    if (t == TPB - 1) partials[blockIdx.x] = tsum[t];
    int run = tsum[t] - tot;
    #pragma unroll
    for (int i = 0; i < SCAN_ITEMS; ++i) {
        if (base + i < n) data[base + i] = run;   // in-place: v[] already read
        run += v[i];
    }
}

__global__ __launch_bounds__(1024) void scan_mid(int* __restrict__ partials, int nb)
{
    __shared__ int tsum[1024];
    int t = threadIdx.x;
    int v = (t < nb) ? partials[t] : 0;
    tsum[t] = v;
    __syncthreads();
    for (int off = 1; off < 1024; off <<= 1) {
        int x = (t >= off) ? tsum[t - off] : 0;
        __syncthreads();
        tsum[t] += x;
        __syncthreads();
    }
    if (t < nb) partials[t] = tsum[t] - v;   // exclusive
}

__global__ __launch_bounds__(TPB) void scan_down(
    int* __restrict__ data, const int* __restrict__ partials, int n)
{
    int t = threadIdx.x;
    int base = blockIdx.x * (TPB * SCAN_ITEMS) + t * SCAN_ITEMS;
    int add = partials[blockIdx.x];
    #pragma unroll
    for (int i = 0; i < SCAN_ITEMS; ++i)
        if (base + i < n) data[base + i] += add;
}

// ---------------- K5: bin-scatter with LDS reorder ----------------
__global__ __launch_bounds__(TPB) void binscatter_kernel(
    const int* __restrict__ src, const int* __restrict__ dst,
    const float* __restrict__ edge_w, const int* __restrict__ scanned,
    uint2* __restrict__ csr, int n_edges, int nbin, int eb)
{
    __shared__ int lb[NBIN_MAX + 1];
    __shared__ int cur[NBIN_MAX];
    __shared__ unsigned short binof[EPB];
    __shared__ uint2 stage[EPB];
    __shared__ int tv[TPB];

    int t = threadIdx.x;
    int blk = xcd_chunk(blockIdx.x, eb);   // same mapping as binhist

    for (int i = t; i < nbin + 1; i += TPB) lb[i] = 0;
    __syncthreads();

    int base = blk * EPB;
    int d[EPT], s[EPT]; float w[EPT];
    #pragma unroll
    for (int k = 0; k < EPT; ++k) {
        int e = base + k * TPB + t;
        bool ok = (e < n_edges);
        d[k] = ok ? dst[e] : -1;
        s[k] = ok ? src[e] : 0;
        w[k] = ok ? edge_w[e] : 0.0f;
        if (ok) atomicAdd(&lb[d[k] >> BINSHIFT], 1);
    }
    __syncthreads();

    // local exclusive scan of lb[0..nbin); total -> lb[nbin]. 5 bins/thread.
    const int NPT = (NBIN_MAX + TPB - 1) / TPB;   // 5
    int b0 = t * NPT;
    int v[NPT];
    #pragma unroll
    for (int i = 0; i < NPT; ++i)
        v[i] = (b0 + i < nbin) ? lb[b0 + i] : 0;
    int tot = 0;
    #pragma unroll
    for (int i = 0; i < NPT; ++i) tot += v[i];
    tv[t] = tot;
    __syncthreads();
    for (int off = 1; off < TPB; off <<= 1) {
        int x = (t >= off) ? tv[t - off] : 0;
        __syncthreads();
        tv[t] += x;
        __syncthreads();
    }
    int run = tv[t] - tot;
    #pragma unroll
    for (int i = 0; i < NPT; ++i) {
        if (b0 + i < nbin) lb[b0 + i] = run;
        run += v[i];
    }
    if (t == TPB - 1) lb[nbin] = tv[t];
    __syncthreads();

    for (int i = t; i < nbin; i += TPB) cur[i] = lb[i];
    __syncthreads();

    #pragma unroll
    for (int k = 0; k < EPT; ++k) {
        if (d[k] >= 0) {
            int bin = d[k] >> BINSHIFT;
            int pos = atomicAdd(&cur[bin], 1);
            // pack: src (17b) | dst_local (6b) << 17
            stage[pos] = make_uint2((unsigned)s[k] | ((unsigned)(d[k] & (BINSZ - 1)) << 17),
                                    __float_as_uint(w[k]));
            binof[pos] = (unsigned short)bin;
        }
    }
    __syncthreads();

    int nval = lb[nbin];
    for (int p = t; p < nval; p += TPB) {
        int bin = binof[p];
        int gpos = scanned[bin * eb + blk] + (p - lb[bin]);
        csr[gpos] = stage[p];
    }
}

// ---------------- K6: per-bin LDS-accumulate + GEMM + sigmoid ----------------
// 1250 blocks (~5/CU), 16.3KB LDS (8 blocks/CU resident). Inner loop batches
// 8 independent row gathers into registers before the 8 ds_adds -> MLP=8/wave
// (R5's failure was 1 outstanding load/wave => 221 cyc/edge).
__global__ __launch_bounds__(TPB) void bin_aggregate_kernel(
    const float* __restrict__ feats, const int* __restrict__ scanned,
    const uint2* __restrict__ csr, const float* __restrict__ Wm,
    const float* __restrict__ bv, float* __restrict__ out,
    int n_nodes, int n_edges, int nbin, int eb)
{
    __shared__ float acc[BINSZ][D];   // 16 KiB; bank = lane%32 -> 2 lanes/bank (free)
    __shared__ float swd[BINSZ];

    int t = threadIdx.x, lane = t & 63, wv = t >> 6;
    int bin = blockIdx.x;
    int lo  = bin << BINSHIFT;

    float wcol[D];
    #pragma unroll
    for (int k2 = 0; k2 < D; ++k2) wcol[k2] = Wm[k2 * D + lane];
    float bias = bv[lane];

    for (int i = t; i < BINSZ * D; i += TPB) ((float*)acc)[i] = 0.0f;
    for (int i = t; i < BINSZ; i += TPB) swd[i] = 0.0f;
    __syncthreads();

    int seg0 = scanned[bin * eb];
    int seg1 = (bin + 1 < nbin) ? scanned[(bin + 1) * eb] : n_edges;

    for (int cb = seg0 + wv * 64; cb < seg1; cb += 256) {
        int idx = cb + lane;
        uint2 rec = (idx < seg1) ? csr[idx] : make_uint2(0u, 0u);  // pad: w=0 no-op

        // per-lane sum_w contribution (one wave-wide LDS atomic per 64 edges)
        atomicAdd(&swd[rec.x >> 17], __uint_as_float(rec.y));

        #pragma unroll
        for (int g = 0; g < 8; ++g) {
            float f_[8], w_[8]; int dl_[8];
            #pragma unroll
            for (int j = 0; j < 8; ++j) {
                int ln = g * 8 + j;   // compile-time after unroll
                unsigned ex = __builtin_amdgcn_readlane(rec.x, ln);
                w_[j]  = __uint_as_float(__builtin_amdgcn_readlane(rec.y, ln));
                dl_[j] = (int)(ex >> 17);
                f_[j]  = feats[(int)(ex & 0x1FFFF) * D + lane];  // 8 independent 256B gathers
            }
            #pragma unroll
            for (int j = 0; j < 8; ++j)
                atomicAdd(&acc[dl_[j]][lane], w_[j] * f_[j]);
        }
    }
    __syncthreads();

    // epilogue: wave wv owns local nodes [wv*16, wv*16+16)
    for (int rsub = 0; rsub < BINSZ / 4; ++rsub) {
        int nl = wv * (BINSZ / 4) + rsub;
        int n  = lo + nl;
        if (n >= n_nodes) break;
        float a  = acc[nl][lane];
        float sw = swd[nl];
        float f  = feats[n * D + lane];
        float h  = (sw > 0.0f) ? a / fmaxf(sw, 1e-30f) : 0.0f;
        float aggv = 0.8f * f + 0.2f * h;
        float racc = bias;
        #pragma unroll
        for (int k2 = 0; k2 < D; ++k2) {
            float ak = __uint_as_float(
                __builtin_amdgcn_readlane(__float_as_uint(aggv), k2));
            racc = fmaf(ak, wcol[k2], racc);
        }
        out[n * D + lane] = 1.0f / (1.0f + __expf(-racc));
    }
}

extern "C" void kernel_launch(void* const* d_in, const int* in_sizes, int n_in,
                              void* d_out, int out_size, void* d_ws, size_t ws_size,
                              hipStream_t stream)
{
    const float* feats  = (const float*)d_in[0];
    const int*   src    = (const int*)d_in[1];
    const int*   dst    = (const int*)d_in[2];
    const float* edge_w = (const float*)d_in[3];
    const float* W      = (const float*)d_in[4];
    const float* b      = (const float*)d_in[5];
    float*       out    = (float*)d_out;

    const int n_nodes = in_sizes[0] / D;
    const int n_edges = in_sizes[1];

    const int NBIN = (n_nodes + BINSZ - 1) / BINSZ;           // 1250
    const int EB   = (n_edges + EPB - 1) / EPB;               // 1250
    const int NBB  = NBIN * EB;                               // 1,562,500
    const int nb   = (NBB + TPB * SCAN_ITEMS - 1) / (TPB * SCAN_ITEMS);  // 763 (<=1024)

    // ---- workspace: blockbin[NBB] (scanned in-place) + partials + csr ----
    int* ws_i     = (int*)d_ws;
    int* blockbin = ws_i;                         // [NBB] counts -> scanned in-place
    int* partials = blockbin + NBB;               // [1024]
    uint2* csr    = (uint2*)(partials + 1024);    // [n_edges] (NBB+1024 even -> 8B aligned)

    binhist_kernel<<<EB, TPB, 0, stream>>>(dst, blockbin, n_edges, NBIN, EB);
    scan_up<<<nb, TPB, 0, stream>>>(blockbin, partials, NBB);
    scan_mid<<<1, 1024, 0, stream>>>(partials, nb);
    scan_down<<<nb, TPB, 0, stream>>>(blockbin, partials, NBB);
    binscatter_kernel<<<EB, TPB, 0, stream>>>(src, dst, edge_w, blockbin, csr,
                                              n_edges, NBIN, EB);
    bin_aggregate_kernel<<<NBIN, TPB, 0, stream>>>(feats, blockbin, csr, W, b,
                                                   out, n_nodes, n_edges, NBIN, EB);
}

// Round 10
// 198.624 us; speedup vs baseline: 3.3472x; 2.9545x over previous
//
#include <hip/hip_runtime.h>

#define D 64
#define TPB 256
#define EPB 2048            // edges per build chunk
#define EPT (EPB / TPB)     // 8 edges per thread in build blocks
#define BINSZ 64            // nodes per bin (bin = dst >> 6)
#define BINSHIFT 6
#define NBIN_MAX 1280       // LDS sizing (actual 1250)
#define SCAN_ITEMS 8
#define CAP 1536            // sorted-stage capacity per bin (mean 1024, 16 sigma)

// bijective chunked XCD swizzle (m204): physical block -> logical chunk so
// blocks resident on one XCD own CONTIGUOUS logical chunks. binhist and
// binscatter MUST use the same mapping.
__device__ __forceinline__ int xcd_chunk(int phys, int nblk)
{
    int q = nblk >> 3, r = nblk & 7;
    int xcd = phys & 7, sub = phys >> 3;
    return (xcd < r ? xcd * (q + 1) : r * (q + 1) + (xcd - r) * q) + sub;
}

// ---------------- K1: per-(chunk,bin) histogram ----------------
__global__ __launch_bounds__(TPB, 4) void binhist_kernel(
    const int* __restrict__ dst, int* __restrict__ blockbin,
    int n_edges, int nbin, int eb)
{
    __shared__ int hist[NBIN_MAX];
    int t = threadIdx.x;
    int blk = xcd_chunk(blockIdx.x, eb);
    for (int i = t; i < nbin; i += TPB) hist[i] = 0;
    __syncthreads();
    int base = blk * EPB;
    #pragma unroll
    for (int k = 0; k < EPT; ++k) {
        int e = base + k * TPB + t;
        if (e < n_edges) atomicAdd(&hist[dst[e] >> BINSHIFT], 1);
    }
    __syncthreads();
    for (int i = t; i < nbin; i += TPB) blockbin[i * eb + blk] = hist[i];
}

// ---------------- 3-kernel exclusive scan (in-place) ----------------
__global__ __launch_bounds__(TPB) void scan_up(
    int* __restrict__ data, int* __restrict__ partials, int n)
{
    __shared__ int tsum[TPB];
    int t = threadIdx.x;
    int base = blockIdx.x * (TPB * SCAN_ITEMS) + t * SCAN_ITEMS;
    int v[SCAN_ITEMS];
    #pragma unroll
    for (int i = 0; i < SCAN_ITEMS; ++i)
        v[i] = (base + i < n) ? data[base + i] : 0;
    int tot = 0;
    #pragma unroll
    for (int i = 0; i < SCAN_ITEMS; ++i) tot += v[i];
    tsum[t] = tot;
    __syncthreads();
    for (int off = 1; off < TPB; off <<= 1) {
        int x = (t >= off) ? tsum[t - off] : 0;
        __syncthreads();
        tsum[t] += x;
        __syncthreads();
    }
    if (t == TPB - 1) partials[blockIdx.x] = tsum[t];
    int run = tsum[t] - tot;
    #pragma unroll
    for (int i = 0; i < SCAN_ITEMS; ++i) {
        if (base + i < n) data[base + i] = run;
        run += v[i];
    }
}

__global__ __launch_bounds__(1024) void scan_mid(int* __restrict__ partials, int nb)
{
    __shared__ int tsum[1024];
    int t = threadIdx.x;
    int v = (t < nb) ? partials[t] : 0;
    tsum[t] = v;
    __syncthreads();
    for (int off = 1; off < 1024; off <<= 1) {
        int x = (t >= off) ? tsum[t - off] : 0;
        __syncthreads();
        tsum[t] += x;
        __syncthreads();
    }
    if (t < nb) partials[t] = tsum[t] - v;   // exclusive
}

__global__ __launch_bounds__(TPB) void scan_down(
    int* __restrict__ data, const int* __restrict__ partials, int n)
{
    int t = threadIdx.x;
    int base = blockIdx.x * (TPB * SCAN_ITEMS) + t * SCAN_ITEMS;
    int add = partials[blockIdx.x];
    #pragma unroll
    for (int i = 0; i < SCAN_ITEMS; ++i)
        if (base + i < n) data[base + i] += add;
}

// ---------------- K5: bin-scatter with LDS reorder ----------------
__global__ __launch_bounds__(TPB, 4) void binscatter_kernel(
    const int* __restrict__ src, const int* __restrict__ dst,
    const float* __restrict__ edge_w, const int* __restrict__ scanned,
    uint2* __restrict__ csr, int n_edges, int nbin, int eb)
{
    __shared__ int lb[NBIN_MAX + 1];
    __shared__ int cur[NBIN_MAX];
    __shared__ unsigned short binof[EPB];
    __shared__ uint2 stage[EPB];
    __shared__ int tv[TPB];

    int t = threadIdx.x;
    int blk = xcd_chunk(blockIdx.x, eb);   // same mapping as binhist

    for (int i = t; i < nbin + 1; i += TPB) lb[i] = 0;
    __syncthreads();

    int base = blk * EPB;
    int d[EPT], s[EPT]; float w[EPT];
    #pragma unroll
    for (int k = 0; k < EPT; ++k) {
        int e = base + k * TPB + t;
        bool ok = (e < n_edges);
        d[k] = ok ? dst[e] : -1;
        s[k] = ok ? src[e] : 0;
        w[k] = ok ? edge_w[e] : 0.0f;
        if (ok) atomicAdd(&lb[d[k] >> BINSHIFT], 1);
    }
    __syncthreads();

    // local exclusive scan of lb[0..nbin); total -> lb[nbin]. 5 bins/thread.
    const int NPT = (NBIN_MAX + TPB - 1) / TPB;   // 5
    int b0 = t * NPT;
    int v[NPT];
    #pragma unroll
    for (int i = 0; i < NPT; ++i)
        v[i] = (b0 + i < nbin) ? lb[b0 + i] : 0;
    int tot = 0;
    #pragma unroll
    for (int i = 0; i < NPT; ++i) tot += v[i];
    tv[t] = tot;
    __syncthreads();
    for (int off = 1; off < TPB; off <<= 1) {
        int x = (t >= off) ? tv[t - off] : 0;
        __syncthreads();
        tv[t] += x;
        __syncthreads();
    }
    int run = tv[t] - tot;
    #pragma unroll
    for (int i = 0; i < NPT; ++i) {
        if (b0 + i < nbin) lb[b0 + i] = run;
        run += v[i];
    }
    if (t == TPB - 1) lb[nbin] = tv[t];
    __syncthreads();

    for (int i = t; i < nbin; i += TPB) cur[i] = lb[i];
    __syncthreads();

    #pragma unroll
    for (int k = 0; k < EPT; ++k) {
        if (d[k] >= 0) {
            int bin = d[k] >> BINSHIFT;
            int pos = atomicAdd(&cur[bin], 1);
            // pack: src (17b) | dst_local (6b) << 17
            stage[pos] = make_uint2((unsigned)s[k] | ((unsigned)(d[k] & (BINSZ - 1)) << 17),
                                    __float_as_uint(w[k]));
            binof[pos] = (unsigned short)bin;
        }
    }
    __syncthreads();

    int nval = lb[nbin];
    for (int p = t; p < nval; p += TPB) {
        int bin = binof[p];
        int gpos = scanned[bin * eb + blk] + (p - lb[bin]);
        csr[gpos] = stage[p];
    }
}

// ---------------- K6: per-bin counting-sort + register-accumulate gather ----------------
// One block per bin (64 dst nodes). Phase A: counting-sort the bin's ~1024
// records by dst_local into LDS (per-dst contiguous runs). Phase B: each wave
// owns whole dst nodes; 8 NAMED-SCALAR edges in flight (no arrays -> no
// scratch, R7 lesson), pure register accumulator, no LDS atomics in the gather
// chain. alpha-blend written to agg (= d_out; each row touched by one wave).
__global__ __launch_bounds__(TPB, 4) void bin_gather_kernel(
    const float* __restrict__ feats, const int* __restrict__ scanned,
    const uint2* __restrict__ csr, float* __restrict__ agg,
    int n_nodes, int n_edges, int nbin, int eb)
{
    __shared__ uint2 stage[CAP];     // 12 KiB sorted records
    __shared__ int   cnt[BINSZ];     // hist -> cursor
    __shared__ int   off[BINSZ + 1]; // per-dst run starts

    int t = threadIdx.x, lane = t & 63, wv = t >> 6;
    int bin = blockIdx.x;
    int lo  = bin << BINSHIFT;

    int seg0 = scanned[bin * eb];
    int seg1 = (bin + 1 < nbin) ? scanned[(bin + 1) * eb] : n_edges;
    int total = seg1 - seg0;

    if (t < BINSZ) cnt[t] = 0;
    __syncthreads();

    // pass 1: histogram by dst_local
    for (int i = t; i < total; i += TPB)
        atomicAdd(&cnt[csr[seg0 + i].x >> 17], 1);
    __syncthreads();

    // wave 0: 64-lane shfl scan -> off[], reset cnt to run starts (cursors)
    if (wv == 0) {
        int c = (lane < BINSZ) ? cnt[lane] : 0;
        int x = c;
        #pragma unroll
        for (int o = 1; o < 64; o <<= 1) {
            int y = __shfl_up(x, o);
            if (lane >= o) x += y;
        }
        if (lane == 0) off[0] = 0;
        if (lane < BINSZ) {
            off[lane + 1] = x;        // inclusive -> off[64] = total
            cnt[lane]     = x - c;    // exclusive start = cursor
        }
    }
    __syncthreads();

    // pass 2: scatter into sorted LDS stage
    for (int i = t; i < total; i += TPB) {
        uint2 r = csr[seg0 + i];
        int pos = atomicAdd(&cnt[r.x >> 17], 1);
        if (pos < CAP) stage[pos] = r;
    }
    __syncthreads();

    // phase B: wave wv processes dst nodes wv, wv+4, ... (16 nodes each)
    for (int nl = wv; nl < BINSZ; nl += 4) {
        int n = lo + nl;
        if (n >= n_nodes) break;
        int i  = off[nl];
        int e2 = off[nl + 1];
        float acc = 0.0f, sumw = 0.0f;
        for (; i + 8 <= e2; i += 8) {
            // 8 broadcast LDS reads (uniform addr) -> 8 independent gathers
            uint2 r0 = stage[i + 0], r1 = stage[i + 1], r2 = stage[i + 2], r3 = stage[i + 3];
            uint2 r4 = stage[i + 4], r5 = stage[i + 5], r6 = stage[i + 6], r7 = stage[i + 7];
            float f0 = feats[(r0.x & 0x1FFFF) * D + lane];
            float f1 = feats[(r1.x & 0x1FFFF) * D + lane];
            float f2 = feats[(r2.x & 0x1FFFF) * D + lane];
            float f3 = feats[(r3.x & 0x1FFFF) * D + lane];
            float f4 = feats[(r4.x & 0x1FFFF) * D + lane];
            float f5 = feats[(r5.x & 0x1FFFF) * D + lane];
            float f6 = feats[(r6.x & 0x1FFFF) * D + lane];
            float f7 = feats[(r7.x & 0x1FFFF) * D + lane];
            float w0 = __uint_as_float(r0.y), w1 = __uint_as_float(r1.y);
            float w2 = __uint_as_float(r2.y), w3 = __uint_as_float(r3.y);
            float w4 = __uint_as_float(r4.y), w5 = __uint_as_float(r5.y);
            float w6 = __uint_as_float(r6.y), w7 = __uint_as_float(r7.y);
            acc = fmaf(w0, f0, acc); acc = fmaf(w1, f1, acc);
            acc = fmaf(w2, f2, acc); acc = fmaf(w3, f3, acc);
            acc = fmaf(w4, f4, acc); acc = fmaf(w5, f5, acc);
            acc = fmaf(w6, f6, acc); acc = fmaf(w7, f7, acc);
            sumw += (w0 + w1) + (w2 + w3) + ((w4 + w5) + (w6 + w7));
        }
        for (; i < e2; ++i) {
            uint2 r = stage[i];
            float w = __uint_as_float(r.y);
            acc = fmaf(w, feats[(r.x & 0x1FFFF) * D + lane], acc);
            sumw += w;
        }
        float f = feats[n * D + lane];
        float h = (sumw > 0.0f) ? acc / fmaxf(sumw, 1e-30f) : 0.0f;
        agg[n * D + lane] = 0.8f * f + 0.2f * h;
    }
}

// ---------------- K7: 64x64 GEMM + bias + sigmoid (in-place on d_out) ----------------
// Separate kernel so wcol[64] has short liveness: __launch_bounds__(256,4)
// grants 128 VGPRs -> no spill. Each row read+written by exactly one wave.
__global__ __launch_bounds__(TPB, 4) void gemm_sigmoid_kernel(
    const float* __restrict__ Wm, const float* __restrict__ bv,
    float* __restrict__ io, int n_nodes)
{
    int lane = threadIdx.x & 63;
    int wave = (blockIdx.x * blockDim.x + threadIdx.x) >> 6;
    int nw   = (gridDim.x * blockDim.x) >> 6;

    float wcol[D];
    #pragma unroll
    for (int k = 0; k < D; ++k) wcol[k] = Wm[k * D + lane];
    float bias = bv[lane];

    for (int n = wave; n < n_nodes; n += nw) {
        float a = io[n * D + lane];
        float r = bias;
        #pragma unroll
        for (int k = 0; k < D; ++k) {
            float ak = __uint_as_float(
                __builtin_amdgcn_readlane(__float_as_uint(a), k));
            r = fmaf(ak, wcol[k], r);
        }
        io[n * D + lane] = 1.0f / (1.0f + __expf(-r));
    }
}

extern "C" void kernel_launch(void* const* d_in, const int* in_sizes, int n_in,
                              void* d_out, int out_size, void* d_ws, size_t ws_size,
                              hipStream_t stream)
{
    const float* feats  = (const float*)d_in[0];
    const int*   src    = (const int*)d_in[1];
    const int*   dst    = (const int*)d_in[2];
    const float* edge_w = (const float*)d_in[3];
    const float* W      = (const float*)d_in[4];
    const float* b      = (const float*)d_in[5];
    float*       out    = (float*)d_out;

    const int n_nodes = in_sizes[0] / D;
    const int n_edges = in_sizes[1];

    const int NBIN = (n_nodes + BINSZ - 1) / BINSZ;           // 1250
    const int EB   = (n_edges + EPB - 1) / EPB;               // 625
    const int NBB  = NBIN * EB;                               // 781,250
    const int nb   = (NBB + TPB * SCAN_ITEMS - 1) / (TPB * SCAN_ITEMS);  // 382 (<=1024)

    // ---- workspace: blockbin[NBB] (scanned in-place) + partials + csr (13.4MB) ----
    int* ws_i     = (int*)d_ws;
    int* blockbin = ws_i;                         // [NBB]
    int* partials = blockbin + NBB;               // [1024]
    uint2* csr    = (uint2*)(partials + 1024);    // [n_edges] (NBB+1024 even -> 8B aligned)

    binhist_kernel<<<EB, TPB, 0, stream>>>(dst, blockbin, n_edges, NBIN, EB);
    scan_up<<<nb, TPB, 0, stream>>>(blockbin, partials, NBB);
    scan_mid<<<1, 1024, 0, stream>>>(partials, nb);
    scan_down<<<nb, TPB, 0, stream>>>(blockbin, partials, NBB);
    binscatter_kernel<<<EB, TPB, 0, stream>>>(src, dst, edge_w, blockbin, csr,
                                              n_edges, NBIN, EB);
    bin_gather_kernel<<<NBIN, TPB, 0, stream>>>(feats, blockbin, csr, out,
                                                n_nodes, n_edges, NBIN, EB);
    gemm_sigmoid_kernel<<<1024, TPB, 0, stream>>>(W, b, out, n_nodes);
}